// Round 11
// baseline (88.460 us; speedup 1.0000x reference)
//
#include <hip/hip_runtime.h>
#include <hip/hip_bf16.h>

#define IN_C 192
#define HW   9600   // 80*120
#define NPIX 128    // pixels per block (8 waves x 16-px strips)

typedef __attribute__((ext_vector_type(8))) short bf16x8;
typedef __attribute__((ext_vector_type(4))) float f32x4;

static __device__ __forceinline__ short f2bf(float f) {
  return __builtin_bit_cast(short, __float2bfloat16(f));   // RNE
}

// Pack W (192x192 fp32, row-major [o][k]) into fragment-sequential bf16:
// frag (fo, kk): 64 lanes x 8 bf16 (16B/lane), lane l -> o = fo*16 + (l&15),
// k = kk*32 + (l>>4)*8 + j. Same k(l,j) convention as the x B-frags, so any
// true intra-fragment k-permutation of the HW layout cancels (validated R1).
__global__ void pack_w_kernel(const float* __restrict__ W, short* __restrict__ wp) {
  int idx = blockIdx.x * 256 + threadIdx.x;   // 0 .. 4607
  if (idx >= 12 * 6 * 64) return;
  int fo  = idx / (6 * 64);
  int rem = idx % (6 * 64);
  int kk  = rem / 64;
  int l   = rem % 64;
  int o   = fo * 16 + (l & 15);
  int kb  = kk * 32 + (l >> 4) * 8;
  bf16x8 v;
#pragma unroll
  for (int j = 0; j < 8; ++j) v[j] = f2bf(W[o * IN_C + kb + j]);
  *reinterpret_cast<bf16x8*>(wp + (size_t)idx * 8) = v;
}

// Per-pixel GEMM D[o][p] = sum_k W[o][k]*x[b][k][p] + bias[o], sub-block scatter.
// EXACTLY R9's structure (best-tier: 50.3us) with ONE change: output stores
// are NON-TEMPORAL (streaming, no-allocate). Theory: the 118MB store stream
// was evicting x from the 256MB L3 between timed replays (FETCH ~= x/2);
// nt stores stop the eviction -> x goes ~fully L3-resident -> HBM fetch ~0.
// Invariants kept (R5/R6 validated): W in LDS via global_load_lds (af reads
// are lgkmcnt) so the K-loop's ONLY vmcnt ops are x prefetches; depth-3
// 4-buffer rotation; no barriers after the prologue; x read once; bias loads
// epilogue-only.
__global__ __launch_bounds__(512, 4) void conv_mfma_kernel(
    const float* __restrict__ x, const short* __restrict__ wp,
    const float* __restrict__ bias, float* __restrict__ out) {
  __shared__ short wl[12 * 6 * 64 * 8];   // 73728 B packed-fragment W

  const int tid  = threadIdx.x;
  const int wid  = tid >> 6;
  const int lane = tid & 63;
  const int c    = lane & 15;
  const int g    = lane >> 4;
  const int b    = blockIdx.y;
  const int p    = blockIdx.x * NPIX + wid * 16 + c;   // this lane's pixel

  // lane's x column base: k = kk*32 + g*8 + j  ->  xp[(kk*32 + j)*HW]
  const float* xp = x + (size_t)b * IN_C * HW + (size_t)(g * 8) * HW + p;

  float xA[8], xB[8], xC[8], xD[8];

#define LOADX(DST, KK)                                                \
  { _Pragma("unroll")                                                 \
    for (int j = 0; j < 8; ++j)                                       \
      DST[j] = xp[(size_t)((KK) * 32 + j) * HW]; }

  // ---- Prologue: x k0..k2 first (long HBM latency), then W -> LDS ----
  LOADX(xA, 0);
  LOADX(xB, 1);
  LOADX(xC, 2);
#pragma unroll
  for (int i = 0; i < 9; ++i) {
    const int chunk = i * 512 + tid;     // 0..4607
    const short* src = wp + (size_t)chunk * 8;
    short* dst = wl + (size_t)chunk * 8;
    __builtin_amdgcn_global_load_lds(
        (const __attribute__((address_space(1))) void*)src,
        (__attribute__((address_space(3))) void*)dst, 16, 0, 0);
  }
  __syncthreads();   // drains W staging (and the x loads); K-loop barrier-free

  f32x4 acc[12];
#pragma unroll
  for (int m = 0; m < 12; ++m) acc[m] = (f32x4)0.0f;

  // af from LDS in batches of 3 (12 transient VGPRs) to bound pressure.
#define KSTEP(CURB, PFB, PFKK, PFEN, KK)                              \
  {                                                                   \
    if (PFEN) { LOADX(PFB, PFKK); }                                   \
    bf16x8 bfr;                                                       \
    _Pragma("unroll")                                                 \
    for (int j = 0; j < 8; ++j) bfr[j] = f2bf(CURB[j]);               \
    _Pragma("unroll")                                                 \
    for (int h = 0; h < 4; ++h) {                                     \
      bf16x8 af[3];                                                   \
      _Pragma("unroll")                                               \
      for (int m = 0; m < 3; ++m)                                     \
        af[m] = *reinterpret_cast<const bf16x8*>(                     \
            wl + (size_t)((((h * 3 + m) * 6 + (KK)) * 64) + lane) * 8); \
      _Pragma("unroll")                                               \
      for (int m = 0; m < 3; ++m)                                     \
        acc[h * 3 + m] = __builtin_amdgcn_mfma_f32_16x16x32_bf16(     \
            af[m], bfr, acc[h * 3 + m], 0, 0, 0);                     \
    }                                                                 \
  }

  KSTEP(xA, xD, 3, true,  0);   // consume k0, prefetch k3 (3-step lead)
  KSTEP(xB, xA, 4, true,  1);   // consume k1, prefetch k4
  KSTEP(xC, xB, 5, true,  2);   // consume k2, prefetch k5
  KSTEP(xD, xA, 0, false, 3);   // consume k3
  KSTEP(xA, xB, 0, false, 4);   // consume k4
  KSTEP(xB, xC, 0, false, 5);   // consume k5
#undef KSTEP
#undef LOADX

  // Epilogue: C/D col = lane&15 (pixel, == c), row = g*4 + r (out-ch).
  // Stores are NON-TEMPORAL: streaming output must not evict x from L3.
  const int hi = p / 120;
  const int wi = p - hi * 120;
#pragma unroll
  for (int mo = 0; mo < 12; ++mo) {
    const int ob = mo * 16 + g * 4;
    const f32x4 bv = *reinterpret_cast<const f32x4*>(bias + ob);
    const f32x4 v  = acc[mo];
#pragma unroll
    for (int r = 0; r < 4; ++r) {
      const int o  = ob + r;
      const int co = o >> 6;
      const int br = (o >> 3) & 7;
      const int bc = o & 7;
      const int idx = ((b * 3 + co) * 640 + br * 80 + hi) * 960 + bc * 120 + wi;
      __builtin_nontemporal_store(v[r] + bv[r], &out[idx]);
    }
  }
}

extern "C" void kernel_launch(void* const* d_in, const int* in_sizes, int n_in,
                              void* d_out, int out_size, void* d_ws, size_t ws_size,
                              hipStream_t stream) {
  const float* x    = (const float*)d_in[0];
  const float* W    = (const float*)d_in[1];
  const float* bias = (const float*)d_in[2];
  float* out = (float*)d_out;
  short* wp  = (short*)d_ws;   // 192*192 bf16 packed-fragment W (73728 B)

  pack_w_kernel<<<18, 256, 0, stream>>>(W, wp);
  dim3 grid(75, 16);  // 75 pixel tiles of 128 (9600 exact), 16 batches
  conv_mfma_kernel<<<grid, 512, 0, stream>>>(x, wp, bias, out);
}

// Round 12
// 57.279 us; speedup vs baseline: 1.5444x; 1.5444x over previous
//
#include <hip/hip_runtime.h>
#include <hip/hip_bf16.h>

#define IN_C 192
#define HW   9600     // 80*120
#define NPIX 256      // pixels per block (16 waves x 16-px strips)
#define PITCHW 258    // LDS px-row pitch in floats (g-group bank split -> 2-way, free)

typedef __attribute__((ext_vector_type(8))) short bf16x8;
typedef __attribute__((ext_vector_type(4))) float f32x4;

static __device__ __forceinline__ short f2bf(float f) {
  return __builtin_bit_cast(short, __float2bfloat16(f));   // RNE
}

// Pack W (192x192 fp32, row-major [o][k]) into fragment-sequential bf16:
// frag (fo, kk): 64 lanes x 8 bf16 (16B/lane), lane l -> o = fo*16 + (l&15),
// k = kk*32 + (l>>4)*8 + j. Same k(l,j) convention as the x B-frags, so any
// true intra-fragment k-permutation of the HW layout cancels (validated R1).
__global__ void pack_w_kernel(const float* __restrict__ W, short* __restrict__ wp) {
  int idx = blockIdx.x * 256 + threadIdx.x;   // 0 .. 4607
  if (idx >= 12 * 6 * 64) return;
  int fo  = idx / (6 * 64);
  int rem = idx % (6 * 64);
  int kk  = rem / 64;
  int l   = rem % 64;
  int o   = fo * 16 + (l & 15);
  int kb  = kk * 32 + (l >> 4) * 8;
  bf16x8 v;
#pragma unroll
  for (int j = 0; j < 8; ++j) v[j] = f2bf(W[o * IN_C + kb + j]);
  *reinterpret_cast<bf16x8*>(wp + (size_t)idx * 8) = v;
}

// Per-pixel GEMM D[o][p] = sum_k W[o][k]*x[b][k][p] + bias[o], sub-block scatter.
// R12 change: x staged to LDS via global_load_lds SIZE 16 (one instr = one
// 1KB px-row) instead of 4B/lane register loads -> 4x wider HBM requests,
// 4x fewer VMEM instructions (R11 analysis: request width is the last
// difference vs the 6.3TB/s copy probe). 1024-thr block, 256-px tile,
// [32][PITCHW] x-tile double-buffered (66KB) + W 73.7KB = 139.8KB LDS,
// 1 block/CU = 16 waves. 2-phase pipeline: stage(kk+1), compute(kk), barrier.
// Invariants kept: W-frag reads are lgkmcnt (LDS); x read once from HBM;
// bias read post-MFMA only; straight-line unrolled bodies (no spill).
__global__ __launch_bounds__(1024, 4) void conv_mfma_kernel(
    const float* __restrict__ x, const short* __restrict__ wp,
    const float* __restrict__ bias, float* __restrict__ out) {
  __shared__ short wl[12 * 6 * 64 * 8];     // 73728 B packed-fragment W
  __shared__ float sx[2][32 * PITCHW];      // 2 x 33024 B x-tile

  const int tid  = threadIdx.x;
  const int wid  = tid >> 6;                // 0..15
  const int lane = tid & 63;
  const int c    = lane & 15;
  const int g    = lane >> 4;
  const int b    = blockIdx.y;
  // tail block overlaps the previous window (duplicate identical stores)
  const int P0   = min((int)blockIdx.x * NPIX, HW - NPIX);

  const float* xb = x + (size_t)b * IN_C * HW + P0;

  // ---- Prologue: packed W -> LDS (L2-resident), 4608 16B chunks ----
#pragma unroll
  for (int i = 0; i < 4; ++i) {
    const int chunk = i * 1024 + tid;
    __builtin_amdgcn_global_load_lds(
        (const __attribute__((address_space(1))) void*)(wp + (size_t)chunk * 8),
        (__attribute__((address_space(3))) void*)(wl + (size_t)chunk * 8), 16, 0, 0);
  }
  if (tid < 512) {
    const int chunk = 4096 + tid;
    __builtin_amdgcn_global_load_lds(
        (const __attribute__((address_space(1))) void*)(wp + (size_t)chunk * 8),
        (__attribute__((address_space(3))) void*)(wl + (size_t)chunk * 8), 16, 0, 0);
  }

  // STAGE tile KK into sx[BUF]: 32 px-rows; wave wid stages rows 2wid,2wid+1.
  // One instr: 64 lanes x 16B = 1024B = the full 256-px row (linear dest).
#define STAGE(BUF, KK)                                                \
  { _Pragma("unroll")                                                 \
    for (int r = 0; r < 2; ++r) {                                     \
      const int row = wid * 2 + r;                                    \
      const float* src = xb + (size_t)((KK) * 32 + row) * HW + lane * 4; \
      float* dst = &sx[(BUF)][row * PITCHW] + lane * 4;               \
      __builtin_amdgcn_global_load_lds(                               \
          (const __attribute__((address_space(1))) void*)src,         \
          (__attribute__((address_space(3))) void*)dst, 16, 0, 0);    \
    } }

  STAGE(0, 0);
  __syncthreads();   // W + buf0 staged (implicit vmcnt(0)+lgkmcnt(0) drain)

  f32x4 acc[12];
#pragma unroll
  for (int m = 0; m < 12; ++m) acc[m] = (f32x4)0.0f;

  // KSTEP: stage next tile (fire-and-forget), consume current from LDS.
  // x B-frag: lane reads x[k=g*8+j][px=wid*16+c]; banks split 2-way (free).
  // af from wl in batches of 3 (12 transient VGPRs).
#define KSTEP(CUR, KK, PFEN)                                          \
  {                                                                   \
    if (PFEN) STAGE((CUR) ^ 1, (KK) + 1);                             \
    bf16x8 bfr;                                                       \
    _Pragma("unroll")                                                 \
    for (int j = 0; j < 8; ++j)                                       \
      bfr[j] = f2bf(sx[(CUR)][(g * 8 + j) * PITCHW + wid * 16 + c]);  \
    _Pragma("unroll")                                                 \
    for (int h = 0; h < 4; ++h) {                                     \
      bf16x8 af[3];                                                   \
      _Pragma("unroll")                                               \
      for (int m = 0; m < 3; ++m)                                     \
        af[m] = *reinterpret_cast<const bf16x8*>(                     \
            wl + (size_t)((((h * 3 + m) * 6 + (KK)) * 64) + lane) * 8); \
      _Pragma("unroll")                                               \
      for (int m = 0; m < 3; ++m)                                     \
        acc[h * 3 + m] = __builtin_amdgcn_mfma_f32_16x16x32_bf16(     \
            af[m], bfr, acc[h * 3 + m], 0, 0, 0);                     \
    }                                                                 \
    __syncthreads();                                                  \
  }

  KSTEP(0, 0, true);
  KSTEP(1, 1, true);
  KSTEP(0, 2, true);
  KSTEP(1, 3, true);
  KSTEP(0, 4, true);
  KSTEP(1, 5, false);
#undef KSTEP
#undef STAGE

  // Epilogue: C/D col = lane&15 (pixel, == c), row = g*4 + r (out-ch).
  const int p  = P0 + wid * 16 + c;
  const int hi = p / 120;
  const int wi = p - hi * 120;
#pragma unroll
  for (int mo = 0; mo < 12; ++mo) {
    const int ob = mo * 16 + g * 4;
    const f32x4 bv = *reinterpret_cast<const f32x4*>(bias + ob);
    const f32x4 v  = acc[mo];
#pragma unroll
    for (int r = 0; r < 4; ++r) {
      const int o  = ob + r;
      const int co = o >> 6;
      const int br = (o >> 3) & 7;
      const int bc = o & 7;
      const int idx = ((b * 3 + co) * 640 + br * 80 + hi) * 960 + bc * 120 + wi;
      out[idx] = v[r] + bv[r];
    }
  }
}

extern "C" void kernel_launch(void* const* d_in, const int* in_sizes, int n_in,
                              void* d_out, int out_size, void* d_ws, size_t ws_size,
                              hipStream_t stream) {
  const float* x    = (const float*)d_in[0];
  const float* W    = (const float*)d_in[1];
  const float* bias = (const float*)d_in[2];
  float* out = (float*)d_out;
  short* wp  = (short*)d_ws;   // 192*192 bf16 packed-fragment W (73728 B)

  pack_w_kernel<<<18, 256, 0, stream>>>(W, wp);
  dim3 grid((HW + NPIX - 1) / NPIX, 16);   // 38 x 16 (tail overlaps)
  conv_mfma_kernel<<<grid, 1024, 0, stream>>>(x, wp, bias, out);
}

// Round 13
// 54.402 us; speedup vs baseline: 1.6260x; 1.0529x over previous
//
#include <hip/hip_runtime.h>
#include <hip/hip_bf16.h>

#define IN_C 192
#define HW   9600   // 80*120
#define NPIX 64     // pixels per block tile (4 strips x 16 px, 2 o-halves)
#define PITCH 66    // x LDS row pitch in floats -> b32 reads 2-way (free)

typedef __attribute__((ext_vector_type(8))) short bf16x8;
typedef __attribute__((ext_vector_type(4))) float f32x4;

static __device__ __forceinline__ short f2bf(float f) {
  return __builtin_bit_cast(short, __float2bfloat16(f));   // RNE
}

// Pack W (192x192 fp32 [o][k]) into K-MAJOR fragment-sequential bf16:
// chunk index = (kk*12 + fo)*64 + lane, so K-slice kk is a contiguous
// 12288B run (per-step LDS staging reads it with 16B chunks).
// lane l of frag (fo,kk): o = fo*16 + (l&15), k = kk*32 + (l>>4)*8 + j
// (same k(l,j) convention as the x B-frags; permutation cancels - R1).
__global__ void pack_w_kernel(const float* __restrict__ W, short* __restrict__ wp) {
  int idx = blockIdx.x * 256 + threadIdx.x;   // 0 .. 4607
  if (idx >= 6 * 12 * 64) return;
  int kk  = idx / (12 * 64);
  int rem = idx % (12 * 64);
  int fo  = rem / 64;
  int l   = rem % 64;
  int o   = fo * 16 + (l & 15);
  int kb  = kk * 32 + (l >> 4) * 8;
  bf16x8 v;
#pragma unroll
  for (int j = 0; j < 8; ++j) v[j] = f2bf(W[o * IN_C + kb + j]);
  *reinterpret_cast<bf16x8*>(wp + (size_t)idx * 8) = v;
}

// Per-pixel GEMM D[o][p] = sum_k W[o][k]*x[b][k][p] + bias[o], sub-block scatter.
// m97-shape 2-barrier K-loop at 3 blocks/CU (the occupancy-cap raiser):
// LDS holds double-buffered per-step W-SLICES (12.3KB) + x-tiles (16.9KB)
// = 41.5KB total -> 3 blocks/CU (75% cap vs 50% for whole-W-in-LDS).
// Block = 8 waves: waves 0-3 compute o[0:96], waves 4-7 o[96:192], SAME
// 64-px x-tile from LDS (x read once from HBM; och-split duplication is
// absorbed by shared LDS - fixes R4). acc = 6 frags = 24 regs -> ~80 VGPR.
// One barrier per K-step; per-step vmcnt drain at the barrier is hidden by
// the other 2 resident blocks (m114 overlap; R12's 1-block/CU had none).
__global__ __launch_bounds__(512, 6) void conv_mfma_kernel(
    const float* __restrict__ x, const short* __restrict__ wp,
    const float* __restrict__ bias, float* __restrict__ out) {
  __shared__ short wsl[2][12 * 64 * 8];      // 2 x 12288 B W K-slice
  __shared__ float sx[2][32 * PITCH];        // 2 x 8448 B x-tile

  const int tid  = threadIdx.x;
  const int wid  = tid >> 6;
  const int lane = tid & 63;
  const int c    = lane & 15;
  const int g    = lane >> 4;
  const int half = wid >> 2;            // o-half: 0 -> o[0:96], 1 -> o[96:192]
  const int sid  = wid & 3;             // px strip within the 64-px tile
  const int b    = blockIdx.y;
  const int ptile = blockIdx.x * NPIX;

  const float* xb = x + (size_t)b * IN_C * HW + ptile;

  // STAGE_X tile KK into sx[BUF]: 32 k-rows x 64 px; wave wid stages rows
  // 4*wid+r (one 256B row per instr, 64 lanes x 4B, linear dest).
#define STAGE_X(BUF, KK)                                              \
  { _Pragma("unroll")                                                 \
    for (int r = 0; r < 4; ++r) {                                     \
      const int row = wid * 4 + r;                                    \
      const float* src = xb + (size_t)((KK) * 32 + row) * HW + lane;  \
      float* dst = &sx[(BUF)][row * PITCH];                           \
      __builtin_amdgcn_global_load_lds(                               \
          (const __attribute__((address_space(1))) void*)src,         \
          (__attribute__((address_space(3))) void*)dst, 4, 0, 0);     \
    } }

  // STAGE_W slice KK into wsl[BUF]: 768 x 16B chunks, contiguous (k-major wp).
#define STAGE_W(BUF, KK)                                              \
  {                                                                   \
    const short* wsrc = wp + (size_t)(KK) * (12 * 64 * 8);            \
    {                                                                 \
      const int chunk = tid;                                          \
      __builtin_amdgcn_global_load_lds(                               \
          (const __attribute__((address_space(1))) void*)(wsrc + (size_t)chunk * 8), \
          (__attribute__((address_space(3))) void*)(wsl[(BUF)] + (size_t)chunk * 8), \
          16, 0, 0);                                                  \
    }                                                                 \
    if (tid < 256) {                                                  \
      const int chunk = 512 + tid;                                    \
      __builtin_amdgcn_global_load_lds(                               \
          (const __attribute__((address_space(1))) void*)(wsrc + (size_t)chunk * 8), \
          (__attribute__((address_space(3))) void*)(wsl[(BUF)] + (size_t)chunk * 8), \
          16, 0, 0);                                                  \
    }                                                                 \
  }

  STAGE_W(0, 0);
  STAGE_X(0, 0);
  __syncthreads();   // prologue staged (vmcnt drained per-wave at barrier)

  f32x4 acc[6];
#pragma unroll
  for (int m = 0; m < 6; ++m) acc[m] = (f32x4)0.0f;

  // KSTEP: stage next (fire-and-forget) -> compute current -> barrier.
  // x B-frag: lane reads sx[k=g*8+j][px=sid*16+c]; PITCH=66 -> 2-way (free).
  // af: lane-contiguous 16B from its o-half's 6 frags (conflict-free b128).
#define KSTEP(CUR, KK, PFEN)                                          \
  {                                                                   \
    if (PFEN) { STAGE_W((CUR) ^ 1, (KK) + 1); STAGE_X((CUR) ^ 1, (KK) + 1); } \
    bf16x8 bfr;                                                       \
    _Pragma("unroll")                                                 \
    for (int j = 0; j < 8; ++j)                                       \
      bfr[j] = f2bf(sx[(CUR)][(g * 8 + j) * PITCH + sid * 16 + c]);   \
    _Pragma("unroll")                                                 \
    for (int m = 0; m < 6; ++m) {                                     \
      const bf16x8 af = *reinterpret_cast<const bf16x8*>(             \
          wsl[(CUR)] + (size_t)(((half * 6 + m) * 64 + lane)) * 8);   \
      acc[m] = __builtin_amdgcn_mfma_f32_16x16x32_bf16(               \
          af, bfr, acc[m], 0, 0, 0);                                  \
    }                                                                 \
    if (PFEN) __syncthreads();                                        \
  }

  KSTEP(0, 0, true);
  KSTEP(1, 1, true);
  KSTEP(0, 2, true);
  KSTEP(1, 3, true);
  KSTEP(0, 4, true);
  KSTEP(1, 5, false);   // last step: no stage, no barrier
#undef KSTEP
#undef STAGE_W
#undef STAGE_X

  // Epilogue: C/D col = lane&15 (pixel, == c), row = g*4 + r (out-ch).
  // bias read here is post-MFMA (no prefetch pending in the epilogue).
  const int p  = ptile + sid * 16 + c;
  const int hi = p / 120;
  const int wi = p - hi * 120;
#pragma unroll
  for (int m = 0; m < 6; ++m) {
    const int ob = (half * 6 + m) * 16 + g * 4;
    const f32x4 bv = *reinterpret_cast<const f32x4*>(bias + ob);
    const f32x4 v  = acc[m];
#pragma unroll
    for (int r = 0; r < 4; ++r) {
      const int o  = ob + r;
      const int co = o >> 6;
      const int br = (o >> 3) & 7;
      const int bc = o & 7;
      const int idx = ((b * 3 + co) * 640 + br * 80 + hi) * 960 + bc * 120 + wi;
      out[idx] = v[r] + bv[r];
    }
  }
}

extern "C" void kernel_launch(void* const* d_in, const int* in_sizes, int n_in,
                              void* d_out, int out_size, void* d_ws, size_t ws_size,
                              hipStream_t stream) {
  const float* x    = (const float*)d_in[0];
  const float* W    = (const float*)d_in[1];
  const float* bias = (const float*)d_in[2];
  float* out = (float*)d_out;
  short* wp  = (short*)d_ws;   // 192*192 bf16 packed W, k-major slices

  pack_w_kernel<<<18, 256, 0, stream>>>(W, wp);
  dim3 grid(150, 16);  // 150 tiles of 64 px (9600 exact), 16 batches
  conv_mfma_kernel<<<grid, 512, 0, stream>>>(x, wp, bias, out);
}